// Round 3
// baseline (111.416 us; speedup 1.0000x reference)
//
#include <hip/hip_runtime.h>
#include <hip/hip_bf16.h>

// GroupProjection: B=256, T=512, F=256, G=8, GF=32, GO=64 -> out [B,T,512] fp32
// M = B*T = 131072 rows. idx input is arange(F) -> contiguous group slices.
//
// R3: remove per-block W staging entirely (it was a latency-serialized
// load->ds_write loop behind a block barrier, killing streaming duty cycle).
// A pre-kernel converts W -> bf16 in MFMA fragment order into d_ws once per
// call; the main kernel is a pure streamer: no LDS, no __syncthreads.
// Bias f32x4 per (g,t,kb) is contiguous in the original bias tensor.

typedef __bf16 bf16x8 __attribute__((ext_vector_type(8)));
typedef float f32x4 __attribute__((ext_vector_type(4)));
typedef unsigned short u16t;

union BF8 {
    u16t u[8];
    bf16x8 v;
};

__device__ __forceinline__ u16t f2bf(float f) {
    // round-to-nearest-even fp32 -> bf16 (inputs are finite normals)
    unsigned u = __builtin_bit_cast(unsigned, f);
    u += 0x7fffu + ((u >> 16) & 1u);
    return (u16t)(u >> 16);
}

constexpr int MROWS = 256 * 512;  // 131072
constexpr int FIN   = 256;
constexpr int OUTD  = 512;
constexpr int WELEM = 8 * 32 * 64;  // 16384

// ---- pre-kernel: W (fp32 [G][GF][GO]) -> bf16 fragment-ordered in d_ws ----
// Fragment (g,t) = 16x16x32 A-operand for outcols t*16..t*16+15 of group g:
//   lane l, elem e  <-  W[g][ k=(l>>4)*8+e ][ n=t*16+(l&15) ]
// Flat ws position: ((g*4+t)*64 + l)*8 + e   (u16)
__global__ void gp_prep(const float* __restrict__ W, u16t* __restrict__ wbf) {
    int i = blockIdx.x * 256 + threadIdx.x;  // flat over W: g*2048 + k*64 + n
    if (i >= WELEM) return;
    int g = i >> 11;
    int k = (i >> 6) & 31;
    int n = i & 63;
    int t = n >> 4;
    int l = (n & 15) | ((k >> 3) << 4);
    int e = k & 7;
    wbf[((((g << 2) | t) * 64) + l) * 8 + e] = f2bf(W[i]);
}

// ---- main kernel: pure streaming, no LDS, no barrier ----
__global__ __launch_bounds__(256, 4)
void gp_kernel(const float* __restrict__ x, const u16t* __restrict__ wbf,
               const float* __restrict__ bias, float* __restrict__ out) {
    const int tid  = threadIdx.x;
    const int lane = tid & 63;
    const int wave = tid >> 6;
    const int r15  = lane & 15;   // x-row within tile AND D^T column
    const int kb   = lane >> 4;   // k-block for frags; outcol nibble for D^T
    const int rowbase = blockIdx.x * 64 + wave * 16;

    // x fragment source: row = rowbase + (lane&15), k = kb*8 + e (contiguous 8)
    const float* xp = x + (size_t)(rowbase + r15) * FIN + kb * 8;
    // D^T layout: col = lane&15 = xrow, row = kb*4 + reg = outcol within tile
    float* op = out + (size_t)(rowbase + r15) * OUTD + kb * 4;

#pragma unroll
    for (int g = 0; g < 8; ++g) {
        const float4* p = reinterpret_cast<const float4*>(xp + g * 32);
        float4 lo = p[0];
        float4 hi = p[1];
        BF8 a;
        a.u[0] = f2bf(lo.x); a.u[1] = f2bf(lo.y);
        a.u[2] = f2bf(lo.z); a.u[3] = f2bf(lo.w);
        a.u[4] = f2bf(hi.x); a.u[5] = f2bf(hi.y);
        a.u[6] = f2bf(hi.z); a.u[7] = f2bf(hi.w);

#pragma unroll
        for (int t = 0; t < 4; ++t) {
            BF8 wfrag;
            wfrag.v = *reinterpret_cast<const bf16x8*>(
                &wbf[((((g << 2) | t) * 64) + lane) * 8]);  // 16B, L1/L2-hot
            // bias for the 4 consecutive outcols this lane owns in tile (g,t):
            // contiguous in the ORIGINAL bias tensor.
            f32x4 acc = *reinterpret_cast<const f32x4*>(
                bias + g * 64 + t * 16 + kb * 4);
            // Swapped operands: D^T = W_frag . x_frag (identical frag layouts)
            acc = __builtin_amdgcn_mfma_f32_16x16x32_bf16(wfrag.v, a.v, acc, 0, 0, 0);
            *reinterpret_cast<f32x4*>(op + g * 64 + t * 16) = acc;
        }
    }
}

extern "C" void kernel_launch(void* const* d_in, const int* in_sizes, int n_in,
                              void* d_out, int out_size, void* d_ws, size_t ws_size,
                              hipStream_t stream) {
    const float* x    = (const float*)d_in[0];
    const float* W    = (const float*)d_in[1];
    const float* bias = (const float*)d_in[2];
    // d_in[3] = idx: arange(F).reshape(G,GF) by construction -> contiguous slices
    float* out = (float*)d_out;
    u16t* wbf  = (u16t*)d_ws;  // 32 KB of fragment-ordered bf16 W

    gp_prep<<<dim3((WELEM + 255) / 256), dim3(256), 0, stream>>>(W, wbf);
    gp_kernel<<<dim3(MROWS / 64), dim3(256), 0, stream>>>(x, wbf, bias, out);
}

// Round 4
// 90.142 us; speedup vs baseline: 1.2360x; 1.2360x over previous
//
#include <hip/hip_runtime.h>
#include <hip/hip_bf16.h>

// GroupProjection: B=256, T=512, F=256, G=8, GF=32, GO=64 -> out [B,T,512] fp32
// M = B*T = 131072 rows. idx input is arange(F) -> contiguous group slices.
//
// R4: full-cache-line stores. Theory: partial-line (64B) store segments
// trigger read-for-ownership fetches of the output stream (+256MB hidden HBM
// reads -> 640MB total = 93% of fill-kernel BW at 99us). Fix: wave-local LDS
// round-trip reshapes each 16x64 D-tile so every global store instruction
// writes 4 x 256B fully-contiguous runs (whole 128B lines).

typedef __bf16 bf16x8 __attribute__((ext_vector_type(8)));
typedef float f32x4 __attribute__((ext_vector_type(4)));
typedef unsigned short u16t;

union BF8 {
    u16t u[8];
    bf16x8 v;
};

__device__ __forceinline__ u16t f2bf(float f) {
    // round-to-nearest-even fp32 -> bf16 (inputs are finite normals)
    unsigned u = __builtin_bit_cast(unsigned, f);
    u += 0x7fffu + ((u >> 16) & 1u);
    return (u16t)(u >> 16);
}

constexpr int MROWS = 256 * 512;  // 131072
constexpr int FIN   = 256;
constexpr int OUTD  = 512;
constexpr int WELEM = 8 * 32 * 64;  // 16384

__global__ __launch_bounds__(256, 3)
void gp_kernel(const float* __restrict__ x, const float* __restrict__ W,
               const float* __restrict__ bias, float* __restrict__ out) {
    // W staged as bf16 in fragment order: frag (g,t) covers outcols
    // n = t*16 + (lane&15), k = (lane>>4)*8 + e. Flat: ((g*4+t)*64 + lane)*8 + e.
    __shared__ __align__(16) u16t lds_w[WELEM];          // 32 KB
    __shared__ __align__(16) float lds_b[OUTD];          // 2 KB
    __shared__ __align__(16) float stag[4][16 * 64];     // 16 KB, 4 KB/wave

    const int tid = threadIdx.x;

    // ---- cooperative W stage (vectorized float4 reads) ----
    const float4* W4 = reinterpret_cast<const float4*>(W);
    for (int i4 = tid; i4 < WELEM / 4; i4 += 256) {
        float4 w = W4[i4];
        int base = i4 * 4;  // flat: g*2048 + k*64 + n, n contiguous
#pragma unroll
        for (int e4 = 0; e4 < 4; ++e4) {
            int i = base + e4;
            int g = i >> 11;
            int k = (i >> 6) & 31;
            int n = i & 63;
            int t = n >> 4;
            int l = (n & 15) | ((k >> 3) << 4);
            int e = k & 7;
            float v = (e4 == 0) ? w.x : (e4 == 1) ? w.y : (e4 == 2) ? w.z : w.w;
            lds_w[((((g << 2) | t) * 64) + l) * 8 + e] = f2bf(v);
        }
    }
    for (int i = tid; i < OUTD; i += 256) lds_b[i] = bias[i];
    __syncthreads();

    const int lane = tid & 63;
    const int wave = tid >> 6;
    const int r15  = lane & 15;   // x-row within tile = D^T column
    const int kb   = lane >> 4;   // k-block for frags; outcol nibble for D^T
    const int rowbase = blockIdx.x * 64 + wave * 16;
    float* swave = stag[wave];

    // x fragment source: row = rowbase + (lane&15), k = kb*8 + e (contiguous 8)
    const float* xp = x + (size_t)(rowbase + r15) * FIN + kb * 8;
    const f32x4* lds_b4 = reinterpret_cast<const f32x4*>(lds_b);

    // Hoist all 16 x loads (64 VGPRs in flight).
    float4 xl[16];
#pragma unroll
    for (int g = 0; g < 8; ++g) {
        const float4* p = reinterpret_cast<const float4*>(xp + g * 32);
        xl[2 * g]     = p[0];
        xl[2 * g + 1] = p[1];
    }

    // Store-side lane mapping (linear): row = 4*i + (lane>>4), chunk = lane&15
    const int srow = lane >> 4;
    const int sc   = lane & 15;

#pragma unroll
    for (int g = 0; g < 8; ++g) {
        float4 lo = xl[2 * g];
        float4 hi = xl[2 * g + 1];
        BF8 a;
        a.u[0] = f2bf(lo.x); a.u[1] = f2bf(lo.y);
        a.u[2] = f2bf(lo.z); a.u[3] = f2bf(lo.w);
        a.u[4] = f2bf(hi.x); a.u[5] = f2bf(hi.y);
        a.u[6] = f2bf(hi.z); a.u[7] = f2bf(hi.w);

        // 4 MFMAs -> wave-local LDS tile [16 rows][16 chunks of f32x4],
        // chunk index XOR-swizzled by (row&7) for bank uniformity.
#pragma unroll
        for (int t = 0; t < 4; ++t) {
            BF8 wfrag;
            wfrag.v = *reinterpret_cast<const bf16x8*>(
                &lds_w[((((g << 2) | t) * 64) + lane) * 8]);
            f32x4 acc = lds_b4[g * 16 + t * 4 + kb];
            acc = __builtin_amdgcn_mfma_f32_16x16x32_bf16(wfrag.v, a.v, acc, 0, 0, 0);
            int c = (t * 4 + kb) ^ (r15 & 7);
            *reinterpret_cast<f32x4*>(&swave[r15 * 64 + c * 4]) = acc;
        }
        // Read back linearly (same XOR) and store 4 rows x 256B contiguous
        // per instruction -> every 128B line written by one instruction.
        // Wave-local LDS reuse: compiler inserts lgkmcnt, no barrier needed.
#pragma unroll
        for (int i = 0; i < 4; ++i) {
            int row = i * 4 + srow;
            int c = sc ^ (row & 7);
            f32x4 v = *reinterpret_cast<const f32x4*>(&swave[row * 64 + c * 4]);
            *reinterpret_cast<f32x4*>(
                out + (size_t)(rowbase + row) * OUTD + g * 64 + sc * 4) = v;
        }
    }
}

extern "C" void kernel_launch(void* const* d_in, const int* in_sizes, int n_in,
                              void* d_out, int out_size, void* d_ws, size_t ws_size,
                              hipStream_t stream) {
    const float* x    = (const float*)d_in[0];
    const float* W    = (const float*)d_in[1];
    const float* bias = (const float*)d_in[2];
    // d_in[3] = idx: arange(F).reshape(G,GF) by construction -> contiguous slices
    float* out = (float*)d_out;

    dim3 grid(MROWS / 64);  // 2048 blocks, 4 waves each (16 rows/wave)
    gp_kernel<<<grid, dim3(256), 0, stream>>>(x, W, bias, out);
}

// Round 5
// 88.409 us; speedup vs baseline: 1.2602x; 1.0196x over previous
//
#include <hip/hip_runtime.h>
#include <hip/hip_bf16.h>

// GroupProjection: B=256, T=512, F=256, G=8, GF=32, GO=64 -> out [B,T,512] fp32
// M = B*T = 131072 rows. idx input is arange(F) -> contiguous group slices.
//
// R5: write-stream DRAM locality. Block = 16 rows; waves split by GROUP
// (wave w owns g=2w,2w+1), W-frags in VGPRs (from pre-kernel-ordered buffer,
// L2-hot), full 16x512 output tile staged in one shared 32KB buffer
// (XOR-swizzled), then stored as a single linear 32KB sweep (1KB contiguous
// per wave instruction). 4 consecutive tiles per block -> 128KB linear write
// region. No per-block W scatter, no partial lines, single write pass.

typedef __bf16 bf16x8 __attribute__((ext_vector_type(8)));
typedef float f32x4 __attribute__((ext_vector_type(4)));
typedef unsigned short u16t;

__device__ __forceinline__ u16t f2bf(float f) {
    unsigned u = __builtin_bit_cast(unsigned, f);
    u += 0x7fffu + ((u >> 16) & 1u);
    return (u16t)(u >> 16);
}

constexpr int MROWS = 256 * 512;  // 131072
constexpr int FIN   = 256;
constexpr int OUTD  = 512;
constexpr int WELEM = 8 * 32 * 64;  // 16384
constexpr int TPB   = 4;            // 16-row tiles per block
constexpr int NBLK  = MROWS / (16 * TPB);  // 2048

// ---- pre-kernel: W (fp32 [G][GF][GO]) -> bf16 fragment-ordered in d_ws ----
// Fragment (g,t): lane l, elem e <- W[g][ k=(l>>4)*8+e ][ n=t*16+(l&15) ]
// Flat ws position: ((g*4+t)*64 + l)*8 + e   (u16)
__global__ void gp_prep(const float* __restrict__ W, u16t* __restrict__ wbf) {
    int i = blockIdx.x * 256 + threadIdx.x;  // flat over W: g*2048 + k*64 + n
    if (i >= WELEM) return;
    int g = i >> 11;
    int k = (i >> 6) & 31;
    int n = i & 63;
    int t = n >> 4;
    int l = (n & 15) | ((k >> 3) << 4);
    int e = k & 7;
    wbf[((((g << 2) | t) * 64) + l) * 8 + e] = f2bf(W[i]);
}

__global__ __launch_bounds__(256, 4)
void gp_main(const float* __restrict__ x, const u16t* __restrict__ wbf,
             const float* __restrict__ bias, float* __restrict__ out) {
    __shared__ __align__(16) float stag[16 * 512];  // 32 KB: one 16-row tile

    const int tid  = threadIdx.x;
    const int lane = tid & 63;
    const int wave = tid >> 6;
    const int r15  = lane & 15;   // x-row within tile = D column
    const int kb   = lane >> 4;   // k-block; outcol nibble of D^T
    const int g0   = wave * 2;    // this wave's first group

    // W fragments for this wave's 2 groups: 8 x dwordx4, L2-hot, once/block.
    bf16x8 wf[8];
#pragma unroll
    for (int fr = 0; fr < 8; ++fr) {
        int g = g0 + (fr >> 2), t = fr & 3;
        wf[fr] = *reinterpret_cast<const bf16x8*>(
            wbf + (size_t)(((g * 4 + t) * 64) + lane) * 8);
    }
    // Store-phase bias: thread's f32x4 column chunk is constant across iters.
    const f32x4 b4 = *reinterpret_cast<const f32x4*>(bias + (tid & 127) * 4);

    const int tile0 = blockIdx.x * TPB;

    float4 cur[4], nxt[4];
#pragma unroll
    for (int gp = 0; gp < 2; ++gp) {
        const float4* p = reinterpret_cast<const float4*>(
            x + (size_t)(tile0 * 16 + r15) * FIN + (g0 + gp) * 32 + kb * 8);
        cur[2 * gp]     = p[0];
        cur[2 * gp + 1] = p[1];
    }

#pragma unroll
    for (int it = 0; it < TPB; ++it) {
        const int tile = tile0 + it;

        // Prefetch next tile's x while this tile computes/stores.
        if (it + 1 < TPB) {
#pragma unroll
            for (int gp = 0; gp < 2; ++gp) {
                const float4* p = reinterpret_cast<const float4*>(
                    x + (size_t)((tile + 1) * 16 + r15) * FIN + (g0 + gp) * 32 + kb * 8);
                nxt[2 * gp]     = p[0];
                nxt[2 * gp + 1] = p[1];
            }
        }

#pragma unroll
        for (int gp = 0; gp < 2; ++gp) {
            float4 lo = cur[2 * gp];
            float4 hi = cur[2 * gp + 1];
            bf16x8 a;
            a[0] = (__bf16)lo.x; a[1] = (__bf16)lo.y;
            a[2] = (__bf16)lo.z; a[3] = (__bf16)lo.w;
            a[4] = (__bf16)hi.x; a[5] = (__bf16)hi.y;
            a[6] = (__bf16)hi.z; a[7] = (__bf16)hi.w;
            const int g = g0 + gp;
#pragma unroll
            for (int t = 0; t < 4; ++t) {
                f32x4 acc = {0.f, 0.f, 0.f, 0.f};
                // D^T = W_frag . x_frag: lane (r15,kb) reg j =
                //   y[row r15][outcol g*64 + t*16 + kb*4 + j]
                acc = __builtin_amdgcn_mfma_f32_16x16x32_bf16(
                    wf[gp * 4 + t], a, acc, 0, 0, 0);
                // stag[row][c4 chunks], c4 XOR-swizzled by row&7:
                // uniform 8 touches/bank (b128 minimum) on write AND read.
                int c4 = (g * 16 + t * 4 + kb) ^ (r15 & 7);
                *reinterpret_cast<f32x4*>(&stag[r15 * 512 + c4 * 4]) = acc;
            }
        }
        __syncthreads();

        // Cooperative linear store: 8 f32x4/thread; each wave instruction
        // writes 1KB contiguous; tile emits 32KB as one sweep.
#pragma unroll
        for (int i = 0; i < 8; ++i) {
            int p   = i * 256 + tid;        // f32x4 index in [16][128]
            int row = p >> 7;
            int c4  = p & 127;
            f32x4 v = *reinterpret_cast<const f32x4*>(
                &stag[row * 512 + (c4 ^ (row & 7)) * 4]);
            v += b4;
            *reinterpret_cast<f32x4*>(
                out + (size_t)tile * 16 * OUTD + (size_t)p * 4) = v;
        }
        __syncthreads();  // WAR: next tile's ds_writes vs this tile's reads

#pragma unroll
        for (int j = 0; j < 4; ++j) cur[j] = nxt[j];
    }
}

extern "C" void kernel_launch(void* const* d_in, const int* in_sizes, int n_in,
                              void* d_out, int out_size, void* d_ws, size_t ws_size,
                              hipStream_t stream) {
    const float* x    = (const float*)d_in[0];
    const float* W    = (const float*)d_in[1];
    const float* bias = (const float*)d_in[2];
    // d_in[3] = idx: arange(F).reshape(G,GF) by construction -> contiguous slices
    float* out = (float*)d_out;
    u16t* wbf  = (u16t*)d_ws;  // 32 KB fragment-ordered bf16 W

    gp_prep<<<dim3((WELEM + 255) / 256), dim3(256), 0, stream>>>(W, wbf);
    gp_main<<<dim3(NBLK), dim3(256), 0, stream>>>(x, wbf, bias, out);
}

// Round 6
// 69.073 us; speedup vs baseline: 1.6130x; 1.2799x over previous
//
#include <hip/hip_runtime.h>
#include <hip/hip_bf16.h>

// GroupProjection: B=256, T=512, F=256, G=8, GF=32, GO=64 -> out [B,T,512] fp32
// M = B*T = 131072 rows. idx input is arange(F) -> contiguous group slices.
//
// R6 = R5 + (a) LDS-only barriers: __syncthreads drains vmcnt(0) every tile,
// exposing prefetch-load latency and store-drain per tile; replace with
// s_waitcnt lgkmcnt(0) + s_barrier + sched_barrier(0) so global loads/stores
// stay in flight across tiles. (b) nontemporal output stores (256MB single-
// touch stream should not allocate in 32MB L2).

typedef __bf16 bf16x8 __attribute__((ext_vector_type(8)));
typedef float f32x4 __attribute__((ext_vector_type(4)));
typedef unsigned short u16t;

__device__ __forceinline__ u16t f2bf(float f) {
    unsigned u = __builtin_bit_cast(unsigned, f);
    u += 0x7fffu + ((u >> 16) & 1u);
    return (u16t)(u >> 16);
}

// Barrier with LDS-ordering only: does NOT drain vmcnt (global loads/stores
// remain in flight). "memory" clobber pins prior LDS ops above the wait;
// sched_barrier(0) pins later ops below the barrier (guide rule #18).
#define BAR_LDS()                                            \
    do {                                                     \
        asm volatile("s_waitcnt lgkmcnt(0)" ::: "memory");   \
        __builtin_amdgcn_s_barrier();                        \
        __builtin_amdgcn_sched_barrier(0);                   \
    } while (0)

constexpr int MROWS = 256 * 512;  // 131072
constexpr int FIN   = 256;
constexpr int OUTD  = 512;
constexpr int WELEM = 8 * 32 * 64;  // 16384
constexpr int TPB   = 4;            // 16-row tiles per block
constexpr int NBLK  = MROWS / (16 * TPB);  // 2048

// ---- pre-kernel: W (fp32 [G][GF][GO]) -> bf16 fragment-ordered in d_ws ----
// Fragment (g,t): lane l, elem e <- W[g][ k=(l>>4)*8+e ][ n=t*16+(l&15) ]
// Flat ws position: ((g*4+t)*64 + l)*8 + e   (u16)
__global__ void gp_prep(const float* __restrict__ W, u16t* __restrict__ wbf) {
    int i = blockIdx.x * 256 + threadIdx.x;  // flat over W: g*2048 + k*64 + n
    if (i >= WELEM) return;
    int g = i >> 11;
    int k = (i >> 6) & 31;
    int n = i & 63;
    int t = n >> 4;
    int l = (n & 15) | ((k >> 3) << 4);
    int e = k & 7;
    wbf[((((g << 2) | t) * 64) + l) * 8 + e] = f2bf(W[i]);
}

__global__ __launch_bounds__(256, 4)
void gp_main(const float* __restrict__ x, const u16t* __restrict__ wbf,
             const float* __restrict__ bias, float* __restrict__ out) {
    __shared__ __align__(16) float stag[16 * 512];  // 32 KB: one 16-row tile

    const int tid  = threadIdx.x;
    const int lane = tid & 63;
    const int wave = tid >> 6;
    const int r15  = lane & 15;   // x-row within tile = D column
    const int kb   = lane >> 4;   // k-block; outcol nibble of D^T
    const int g0   = wave * 2;    // this wave's first group

    // W fragments for this wave's 2 groups: 8 x dwordx4, L2-hot, once/block.
    bf16x8 wf[8];
#pragma unroll
    for (int fr = 0; fr < 8; ++fr) {
        int g = g0 + (fr >> 2), t = fr & 3;
        wf[fr] = *reinterpret_cast<const bf16x8*>(
            wbf + (size_t)(((g * 4 + t) * 64) + lane) * 8);
    }
    // Store-phase bias: thread's f32x4 column chunk is constant across iters.
    const f32x4 b4 = *reinterpret_cast<const f32x4*>(bias + (tid & 127) * 4);

    const int tile0 = blockIdx.x * TPB;

    float4 cur[4], nxt[4];
#pragma unroll
    for (int gp = 0; gp < 2; ++gp) {
        const float4* p = reinterpret_cast<const float4*>(
            x + (size_t)(tile0 * 16 + r15) * FIN + (g0 + gp) * 32 + kb * 8);
        cur[2 * gp]     = p[0];
        cur[2 * gp + 1] = p[1];
    }

#pragma unroll
    for (int it = 0; it < TPB; ++it) {
        const int tile = tile0 + it;

        // Prefetch next tile's x; with LDS-only barriers these loads stay in
        // flight across both barriers (no vmcnt(0) drain).
        if (it + 1 < TPB) {
#pragma unroll
            for (int gp = 0; gp < 2; ++gp) {
                const float4* p = reinterpret_cast<const float4*>(
                    x + (size_t)((tile + 1) * 16 + r15) * FIN + (g0 + gp) * 32 + kb * 8);
                nxt[2 * gp]     = p[0];
                nxt[2 * gp + 1] = p[1];
            }
        }

#pragma unroll
        for (int gp = 0; gp < 2; ++gp) {
            float4 lo = cur[2 * gp];
            float4 hi = cur[2 * gp + 1];
            bf16x8 a;
            a[0] = (__bf16)lo.x; a[1] = (__bf16)lo.y;
            a[2] = (__bf16)lo.z; a[3] = (__bf16)lo.w;
            a[4] = (__bf16)hi.x; a[5] = (__bf16)hi.y;
            a[6] = (__bf16)hi.z; a[7] = (__bf16)hi.w;
            const int g = g0 + gp;
#pragma unroll
            for (int t = 0; t < 4; ++t) {
                f32x4 acc = {0.f, 0.f, 0.f, 0.f};
                // D^T = W_frag . x_frag: lane (r15,kb) reg j =
                //   y[row r15][outcol g*64 + t*16 + kb*4 + j]
                acc = __builtin_amdgcn_mfma_f32_16x16x32_bf16(
                    wf[gp * 4 + t], a, acc, 0, 0, 0);
                // stag[row][c4 chunks], c4 XOR-swizzled by row&7:
                // uniform bank spread on write AND read.
                int c4 = (g * 16 + t * 4 + kb) ^ (r15 & 7);
                *reinterpret_cast<f32x4*>(&stag[r15 * 512 + c4 * 4]) = acc;
            }
        }
        BAR_LDS();  // ds_writes visible to all waves; vmem stays in flight

        // Cooperative linear store: 8 f32x4/thread; each wave instruction
        // writes 1KB contiguous; tile emits 32KB as one sweep. Nontemporal:
        // single-touch stream, don't allocate in L2.
#pragma unroll
        for (int i = 0; i < 8; ++i) {
            int p   = i * 256 + tid;        // f32x4 index in [16][128]
            int row = p >> 7;
            int c4  = p & 127;
            f32x4 v = *reinterpret_cast<const f32x4*>(
                &stag[row * 512 + (c4 ^ (row & 7)) * 4]);
            v += b4;
            __builtin_nontemporal_store(
                v, reinterpret_cast<f32x4*>(
                       out + (size_t)tile * 16 * OUTD + (size_t)p * 4));
        }
        BAR_LDS();  // ds_reads done before next tile's ds_writes (WAR)

#pragma unroll
        for (int j = 0; j < 4; ++j) cur[j] = nxt[j];
    }
}

extern "C" void kernel_launch(void* const* d_in, const int* in_sizes, int n_in,
                              void* d_out, int out_size, void* d_ws, size_t ws_size,
                              hipStream_t stream) {
    const float* x    = (const float*)d_in[0];
    const float* W    = (const float*)d_in[1];
    const float* bias = (const float*)d_in[2];
    // d_in[3] = idx: arange(F).reshape(G,GF) by construction -> contiguous slices
    float* out = (float*)d_out;
    u16t* wbf  = (u16t*)d_ws;  // 32 KB fragment-ordered bf16 W

    gp_prep<<<dim3((WELEM + 255) / 256), dim3(256), 0, stream>>>(W, wbf);
    gp_main<<<dim3(NBLK), dim3(256), 0, stream>>>(x, wbf, bias, out);
}